// Round 20
// baseline (88.475 us; speedup 1.0000x reference)
//
#include <hip/hip_runtime.h>
#include <hip/hip_fp16.h>

// FeatureSimilarityLoss: E=640000 edges, D=128, NUM_S=50000 (fixed).
// loss = mean over valid s of Σ_{e∈s} w_e ||a_e - mean_s||², mean_s = F_s/(w_s+1e-8)
// Expanded: var_s = S2_s - ||F_s||²·inv·(2 - w_s·inv);  ||F_s||² = Σ_slices ||F_s[slice]||²
// S2_s = Σ_e w_e·sqnorm[a_e], sqnorm from the SAME quantized features (identity exact).
//
// Journal: R1 atomics (1136) -> R2 sort+reg (307) -> R3 MLP (264) -> R4 bf16
// slices (163) -> R5 fused zero (155) -> R6 grid.sync REJ -> R7 XCD-pin REJ ->
// R8 sqnorm (152) -> R9 fence@2048 REJ -> R10 scatter_xcd NEUT -> R11 bucket+2s
// (108) -> R12 4-s REJ -> R13 u32 NEUT -> R14 p-outer RMW merge REJ (replay) ->
// R15 2-deep slice GOOD -> R16 bucket_xcd marginal (102.9) -> R17 fp8 2-pass
// (91.3) -> R18 two-phase binning (83.6) -> R19 disjoint-output slice merge
// (79.5; each node boundary ~4us; bucket round-trip = 1 kernel + 26MB traffic).
// R20: fuse final_bucket INTO the slice kernel: block=(bin,role), LDS-local
// sort (count/scan/scatter) then the proven gather loop with LDS metadata.
// bucket/cnt arrays deleted. 5 -> 4 nodes. Pure writes -> replay-safe.

#define D  128
#define NS 50000
#define NBINS 391    // ceil(NS/128)
#define BIN_CAP 2048 // Poisson(1636)+10sigma

typedef unsigned long long ull;
typedef float f32x2 __attribute__((ext_vector_type(2)));

// ---------- A: accum zero + cursor init + transpose af -> fp8 slices + sqnorm ----------

__global__ void prep_kernel(const float* __restrict__ af, unsigned char* __restrict__ af_q,
                            float* __restrict__ sqnorm, float* __restrict__ accum,
                            int* __restrict__ done, unsigned* __restrict__ binCursor,
                            int num_a) {
    int gtid   = blockIdx.x * 256 + threadIdx.x;
    int stride = gridDim.x * 256;
    if (gtid == 0) { accum[0] = 0.f; accum[1] = 0.f; *done = 0; }
    for (int b = gtid; b < NBINS; b += stride)
        binCursor[b * 16] = (unsigned)b * BIN_CAP;      // absolute base, 64B-padded

    for (int u = gtid; u < num_a * 16; u += stride) {
        int a    = u >> 4;
        int comp = (u & 15) << 3;          // 8 comps per thread
        const float* src = af + (size_t)a * D + comp;
        float4 v0 = *reinterpret_cast<const float4*>(src);
        float4 v1 = *reinterpret_cast<const float4*>(src + 4);
        unsigned lo = __builtin_amdgcn_cvt_pk_fp8_f32(v0.x, v0.y, 0u, false);
        lo = __builtin_amdgcn_cvt_pk_fp8_f32(v0.z, v0.w, lo, true);
        unsigned hi = __builtin_amdgcn_cvt_pk_fp8_f32(v1.x, v1.y, 0u, false);
        hi = __builtin_amdgcn_cvt_pk_fp8_f32(v1.z, v1.w, hi, true);
        int p  = comp >> 6;                // slice 0..1
        int cc = comp & 63;                // byte offset within 64B row
        *reinterpret_cast<ull*>(af_q + ((size_t)p * num_a + a) * 64 + cc) =
            ((ull)hi << 32) | (ull)lo;

        // sum of squares of the DECODED fp8 values (keeps the identity exact)
        f32x2 q0 = __builtin_amdgcn_cvt_pk_f32_fp8(lo, false);
        f32x2 q1 = __builtin_amdgcn_cvt_pk_f32_fp8(lo, true);
        f32x2 q2 = __builtin_amdgcn_cvt_pk_f32_fp8(hi, false);
        f32x2 q3 = __builtin_amdgcn_cvt_pk_f32_fp8(hi, true);
        float ss = q0.x*q0.x + q0.y*q0.y + q1.x*q1.x + q1.y*q1.y
                 + q2.x*q2.x + q2.y*q2.y + q3.x*q3.x + q3.y*q3.y;
        #pragma unroll
        for (int m = 1; m <= 8; m <<= 1) ss += __shfl_xor(ss, m, 64);
        if ((u & 15) == 0) sqnorm[a] = ss;
    }
}

// ---------- B: coarse bin pass — LDS hist + 1 global atomic per (block,bin) ----------

__global__ __launch_bounds__(256) void bin_pass(
    const int* __restrict__ s_idx,
    const int* __restrict__ a_idx,
    const float* __restrict__ ew,
    unsigned* __restrict__ binCursor,     // [NBINS*16] absolute cursors
    ull* __restrict__ coarse, int E)
{
    __shared__ unsigned hist[NBINS];
    __shared__ unsigned base[NBINS];
    int nb    = gridDim.x;
    int chunk = (E + nb - 1) / nb;
    int e0    = blockIdx.x * chunk;
    int e1    = min(E, e0 + chunk);

    for (int t = threadIdx.x; t < NBINS; t += 256) hist[t] = 0;
    __syncthreads();
    for (int i = e0 + (int)threadIdx.x; i < e1; i += 256)
        atomicAdd(&hist[(unsigned)s_idx[i] >> 7], 1u);
    __syncthreads();
    for (int t = threadIdx.x; t < NBINS; t += 256) {
        unsigned c = hist[t];
        base[t] = c ? atomicAdd(&binCursor[t * 16], c) : 0u;
        hist[t] = 0;                       // reuse as local rank counter
    }
    __syncthreads();
    for (int i = e0 + (int)threadIdx.x; i < e1; i += 256) {
        int s = s_idx[i];
        unsigned bin = (unsigned)s >> 7;
        unsigned r   = atomicAdd(&hist[bin], 1u);
        unsigned pos = base[bin] + r;
        if (pos < (bin + 1) * BIN_CAP) {   // safety clamp (never fires for this input)
            unsigned low = ((unsigned)a_idx[i] << 16)
                         | (unsigned)__half_as_ushort(__float2half(ew[i]));
            coarse[pos] = ((ull)((unsigned)s & 127u) << 32) | (ull)low;
        }
    }
}

// decode 16 fp8 (uint4) and FMA into acc[16] with weight w
__device__ __forceinline__ void fma16(const uint4& x, float w, float* acc) {
    f32x2 t;
    t = __builtin_amdgcn_cvt_pk_f32_fp8(x.x, false); acc[0]  += w*t.x; acc[1]  += w*t.y;
    t = __builtin_amdgcn_cvt_pk_f32_fp8(x.x, true);  acc[2]  += w*t.x; acc[3]  += w*t.y;
    t = __builtin_amdgcn_cvt_pk_f32_fp8(x.y, false); acc[4]  += w*t.x; acc[5]  += w*t.y;
    t = __builtin_amdgcn_cvt_pk_f32_fp8(x.y, true);  acc[6]  += w*t.x; acc[7]  += w*t.y;
    t = __builtin_amdgcn_cvt_pk_f32_fp8(x.z, false); acc[8]  += w*t.x; acc[9]  += w*t.y;
    t = __builtin_amdgcn_cvt_pk_f32_fp8(x.z, true);  acc[10] += w*t.x; acc[11] += w*t.y;
    t = __builtin_amdgcn_cvt_pk_f32_fp8(x.w, false); acc[12] += w*t.x; acc[13] += w*t.y;
    t = __builtin_amdgcn_cvt_pk_f32_fp8(x.w, true);  acc[14] += w*t.x; acc[15] += w*t.y;
}

// ---------- C: fused per-bin bucketing + slice accumulation ----------
// Block = (bin, role). Phase 1: LDS-local sort of the bin's edges (count/scan/
// scatter; coarse re-read is L2/L3-hot). Phase 2: proven 2-s x 2-deep gather
// loop, metadata from LDS. Role 0 (slice 0): fn2a + s2acc + wsumv; role 1
// (slice 1): fn2b. One writer per location -> no RMW -> replay-safe.

__global__ __launch_bounds__(256) void bin_slice(
    const ull* __restrict__ coarse,
    const unsigned* __restrict__ binCursor,
    const unsigned char* __restrict__ af_q,   // [2][num_a][64] fp8
    const float* __restrict__ sqnorm,
    float* __restrict__ fn2a, float* __restrict__ fn2b,
    float* __restrict__ s2acc, float* __restrict__ wsumv,
    int num_s, int num_a)
{
    __shared__ unsigned sorted[BIN_CAP];   // 8KB: bin's edges grouped by s7
    __shared__ unsigned lcnt[128];
    __shared__ unsigned loff[128];
    __shared__ unsigned lcur[128];

    const bool p0  = (blockIdx.x & 1u) == 0u;
    const int  bin = blockIdx.x >> 1;
    const unsigned char* afp = af_q + (p0 ? 0 : (size_t)num_a * 64);
    const int tid = threadIdx.x;

    const unsigned start = (unsigned)bin * BIN_CAP;
    const unsigned n = min(binCursor[bin * 16] - start, (unsigned)BIN_CAP);

    // phase 1a: count per s7
    if (tid < 128) lcnt[tid] = 0;
    __syncthreads();
    for (unsigned i = tid; i < n; i += 256)
        atomicAdd(&lcnt[(unsigned)(coarse[start + i] >> 32)], 1u);
    __syncthreads();
    // phase 1b: exclusive scan of 128 counts (wave 0)
    if (tid < 64) {
        unsigned v0 = lcnt[tid], v1 = lcnt[64 + tid];
        unsigned i0 = v0, i1 = v1;
        #pragma unroll
        for (int d = 1; d < 64; d <<= 1) {
            unsigned t0 = __shfl_up(i0, d, 64);
            unsigned t1 = __shfl_up(i1, d, 64);
            if (tid >= d) { i0 += t0; i1 += t1; }
        }
        unsigned tot0 = __shfl(i0, 63, 64);
        loff[tid]      = i0 - v0;         lcur[tid]      = i0 - v0;
        loff[64 + tid] = tot0 + i1 - v1;  lcur[64 + tid] = tot0 + i1 - v1;
    }
    __syncthreads();
    // phase 1c: scatter into LDS, grouped by s7 (coarse re-read: L2/L3-hot)
    for (unsigned i = tid; i < n; i += 256) {
        ull e = coarse[start + i];
        unsigned r = atomicAdd(&lcur[(unsigned)(e >> 32)], 1u);
        sorted[r] = (unsigned)e;
    }
    __syncthreads();

    // phase 2: 8 groups x 32 lanes; group handles 16 s7's as 8 sequential pairs
    int group = tid >> 5;
    int lane  = tid & 31;
    int j     = lane >> 2;       // edge slot 0..7
    int ccq   = lane & 3;        // 16B chunk (16 comps)

    for (int p = 0; p < 8; ++p) {
        int s7a = group * 16 + p * 2;
        int sA  = bin * 128 + s7a;           // even; sA+1 < num_s whenever sA < num_s
        if (sA >= num_s) break;
        int c0 = (int)lcnt[s7a], c1 = (int)lcnt[s7a + 1];
        int base0 = (int)loff[s7a], base1 = (int)loff[s7a + 1];

        float accA[16] = {};
        float accB[16] = {};
        float s2A = 0.f, wlA = 0.f, s2B = 0.f, wlB = 0.f;

        int cmax  = max(c0, c1);
        int iters = (cmax + 15) >> 4;        // 16 edges per s per iteration
        for (int it = 0; it < iters; ++it) {
            int idxA = it * 16 + j;          // slots j and j+8
            int idxB = idxA + 8;
            unsigned wa0  = (idxA < c0) ? sorted[base0 + idxA] : 0u;  // inactive -> w=+0, row 0
            unsigned wa0b = (idxB < c0) ? sorted[base0 + idxB] : 0u;
            unsigned wa1  = (idxA < c1) ? sorted[base1 + idxA] : 0u;
            unsigned wa1b = (idxB < c1) ? sorted[base1 + idxB] : 0u;
            float w0  = __half2float(__ushort_as_half((unsigned short)(wa0  & 0xFFFFu)));
            float w0b = __half2float(__ushort_as_half((unsigned short)(wa0b & 0xFFFFu)));
            float w1  = __half2float(__ushort_as_half((unsigned short)(wa1  & 0xFFFFu)));
            float w1b = __half2float(__ushort_as_half((unsigned short)(wa1b & 0xFFFFu)));
            int A0  = (int)(wa0  >> 16);
            int A0b = (int)(wa0b >> 16);
            int A1  = (int)(wa1  >> 16);
            int A1b = (int)(wa1b >> 16);
            uint4 x  = *reinterpret_cast<const uint4*>(afp + ((size_t)A0  << 6) + (ccq << 4));
            uint4 xb = *reinterpret_cast<const uint4*>(afp + ((size_t)A0b << 6) + (ccq << 4));
            uint4 y  = *reinterpret_cast<const uint4*>(afp + ((size_t)A1  << 6) + (ccq << 4));
            uint4 yb = *reinterpret_cast<const uint4*>(afp + ((size_t)A1b << 6) + (ccq << 4));
            fma16(x,  w0,  accA);
            fma16(xb, w0b, accA);
            fma16(y,  w1,  accB);
            fma16(yb, w1b, accB);
            if (p0 && ccq == 0) {
                s2A += w0 * sqnorm[A0] + w0b * sqnorm[A0b];  wlA += w0 + w0b;
                s2B += w1 * sqnorm[A1] + w1b * sqnorm[A1b];  wlB += w1 + w1b;
            }
        }
        // reduce over edge slots j (lane bits 2..4)
        #pragma unroll
        for (int m = 4; m <= 16; m <<= 1) {
            #pragma unroll
            for (int k = 0; k < 16; ++k) {
                accA[k] += __shfl_xor(accA[k], m, 64);
                accB[k] += __shfl_xor(accB[k], m, 64);
            }
            if (p0) {
                s2A += __shfl_xor(s2A, m, 64); wlA += __shfl_xor(wlA, m, 64);
                s2B += __shfl_xor(s2B, m, 64); wlB += __shfl_xor(wlB, m, 64);
            }
        }
        float n2a = 0.f, n2b = 0.f;
        #pragma unroll
        for (int k = 0; k < 16; ++k) { n2a += accA[k] * accA[k]; n2b += accB[k] * accB[k]; }
        n2a += __shfl_xor(n2a, 1, 64); n2a += __shfl_xor(n2a, 2, 64);
        n2b += __shfl_xor(n2b, 1, 64); n2b += __shfl_xor(n2b, 2, 64);
        if (lane == 0) {   // exclusive (bin, role, s) owner — pure writes only
            if (p0) {
                fn2a[sA]     = n2a;  s2acc[sA]     = s2A;  wsumv[sA]     = wlA;
                fn2a[sA + 1] = n2b;  s2acc[sA + 1] = s2B;  wsumv[sA + 1] = wlB;
            } else {
                fn2b[sA]     = n2a;
                fn2b[sA + 1] = n2b;
            }
        }
    }
}

// ---------- D: loss reduction + last-block finalize (128 blocks: fence cost OK) ----------

__global__ void loss_finalize(const float* __restrict__ fn2a, const float* __restrict__ fn2b,
                              const float* __restrict__ s2acc, const float* __restrict__ wsumv,
                              float* __restrict__ accum, int* __restrict__ done,
                              float* __restrict__ out, int num_s) {
    __shared__ float sv[4], sc[4];
    float lv = 0.f, lc = 0.f;
    for (int s = blockIdx.x * blockDim.x + threadIdx.x; s < num_s; s += gridDim.x * blockDim.x) {
        float w = wsumv[s];
        if (w > 0.f) {
            float n2  = fn2a[s] + fn2b[s];
            float inv = 1.f / (w + 1e-8f);
            lv += s2acc[s] - n2 * inv * (2.f - w * inv);
            lc += 1.f;
        }
    }
    #pragma unroll
    for (int m = 1; m < 64; m <<= 1) { lv += __shfl_xor(lv, m, 64); lc += __shfl_xor(lc, m, 64); }
    int wv = threadIdx.x >> 6;
    if ((threadIdx.x & 63) == 0) { sv[wv] = lv; sc[wv] = lc; }
    __syncthreads();
    if (threadIdx.x == 0) {
        atomicAdd(accum + 0, sv[0] + sv[1] + sv[2] + sv[3]);
        atomicAdd(accum + 1, sc[0] + sc[1] + sc[2] + sc[3]);
        __threadfence();
        unsigned t = atomicAdd((unsigned*)done, 1u);
        if (t == gridDim.x - 1) {
            float v = atomicAdd(accum + 0, 0.f);   // device-scope RMW read
            float c = atomicAdd(accum + 1, 0.f);
            out[0] = (c > 0.f) ? (v / fmaxf(c, 1.f)) : 0.f;
        }
    }
}

extern "C" void kernel_launch(void* const* d_in, const int* in_sizes, int n_in,
                              void* d_out, int out_size, void* d_ws, size_t ws_size,
                              hipStream_t stream) {
    const float* ew = (const float*)d_in[0];          // [E]
    const float* af = (const float*)d_in[1];          // [NA, 128]
    const int*   ei = (const int*)d_in[2];            // [2, E] flat int32
    const int E     = in_sizes[0];
    const int num_a = in_sizes[1] / D;
    const int num_s = NS;

    const int* s_idx = ei;
    const int* a_idx = ei + E;

    // workspace carve-out (~14MB)
    char* ws = (char*)d_ws;
    size_t off = 0;
    auto alloc = [&](size_t bytes, size_t align) -> char* {
        off = (off + align - 1) & ~(align - 1);
        char* p = ws + off;
        off += bytes;
        return p;
    };
    float* accum  = (float*)alloc(4 * 4, 16);          // accum[2] | done | pad
    int*   done   = (int*)(accum + 2);
    float* fn2a   = (float*)alloc((size_t)num_s * 4, 16);
    float* fn2b   = (float*)alloc((size_t)num_s * 4, 16);
    float* s2acc  = (float*)alloc((size_t)num_s * 4, 16);
    float* wsumv  = (float*)alloc((size_t)num_s * 4, 16);
    float* sqnorm = (float*)alloc((size_t)num_a * 4, 16);
    unsigned* binCursor = (unsigned*)alloc((size_t)NBINS * 16 * 4, 64);       // padded cursors
    unsigned char* af_q = (unsigned char*)alloc((size_t)2 * num_a * 64, 256); // 6.4MB fp8
    ull* coarse = (ull*)alloc((size_t)NBINS * BIN_CAP * 8, 512);              // 6.4MB

    prep_kernel<<<(num_a * 16 + 255) / 256, 256, 0, stream>>>(af, af_q, sqnorm, accum, done,
                                                              binCursor, num_a);
    bin_pass<<<256, 256, 0, stream>>>(s_idx, a_idx, ew, binCursor, coarse, E);
    bin_slice<<<NBINS * 2, 256, 0, stream>>>(coarse, binCursor, af_q, sqnorm,
                                             fn2a, fn2b, s2acc, wsumv, num_s, num_a);
    loss_finalize<<<128, 256, 0, stream>>>(fn2a, fn2b, s2acc, wsumv, accum, done,
                                           (float*)d_out, num_s);
}

// Round 21
// 71.557 us; speedup vs baseline: 1.2364x; 1.2364x over previous
//
#include <hip/hip_runtime.h>
#include <hip/hip_fp16.h>

// FeatureSimilarityLoss: E=640000 edges, D=128, NUM_S=50000 (fixed).
// loss = mean over valid s of Σ_{e∈s} w_e ||a_e - mean_s||², mean_s = F_s/(w_s+1e-8)
// Expanded: var_s = S2_s - ||F_s||²·inv·(2 - w_s·inv);  ||F_s||² = Σ_slices ||F_s[slice]||²
// S2_s = Σ_e w_e·sqnorm[a_e], sqnorm from the SAME quantized features (identity exact).
//
// Journal: R1 atomics (1136) -> ... -> R17 fp8 2-pass (91.3) -> R18 two-phase
// binning (83.6) -> R19 disjoint-output slice merge (79.5) -> R20 bin_slice
// fusion REJECTED (88.5; 782 blocks = 19% occupancy starved the gather's TLP —
// gather needs >=4K blocks; R7 lesson repeated).
// R21: R19 skeleton, but binning made cursor-free (per-block private regions,
// pure writes) -> prep and bin have NO dependency -> merged into ONE kernel
// with disjoint block roles (0..255 bin, rest prep). 5 -> 4 nodes; BW-bound
// prep overlaps latency-bound binning. slice_merged/loss_finalize unchanged.

#define D  128
#define NS 50000
#define KMAX 64      // max edges per s; Poisson(12.8) => P(overflow) ~ 1e-18
#define NBINS 391    // ceil(NS/128)
#define CAP_PB 32    // per-(bin,block) region cap; Poisson(6.4), P(>32)~1e-28

typedef unsigned long long ull;
typedef float f32x2 __attribute__((ext_vector_type(2)));

// ---------- A: merged prep + coarse binning (disjoint block roles) ----------
// Role bin (blocks 0..255): block b histograms its E/256 chunk into LDS, writes
// blkCnt[t*256+b] and its edges into private region coarse[(t*256+b)*CAP_PB..]
// — pure writes, no global atomics, no cursors.
// Role prep (blocks 256..): af -> fp8 af_q[2][NA][64] + sqnorm + accum/done init.

__global__ __launch_bounds__(256) void prep_bin(
    const float* __restrict__ af, unsigned char* __restrict__ af_q,
    float* __restrict__ sqnorm, float* __restrict__ accum, int* __restrict__ done,
    const int* __restrict__ s_idx, const int* __restrict__ a_idx,
    const float* __restrict__ ew,
    unsigned* __restrict__ blkCnt,      // [NBINS*256]
    ull* __restrict__ coarse,           // [NBINS*256*CAP_PB]
    int E, int num_a)
{
    __shared__ unsigned hist[NBINS];
    const int tid = threadIdx.x;

    if (blockIdx.x < 256) {
        // ---- bin role ----
        const int b     = blockIdx.x;
        const int chunk = (E + 255) / 256;
        const int e0    = b * chunk;
        const int e1    = min(E, e0 + chunk);

        for (int t = tid; t < NBINS; t += 256) hist[t] = 0;
        __syncthreads();
        for (int i = e0 + tid; i < e1; i += 256)
            atomicAdd(&hist[(unsigned)s_idx[i] >> 7], 1u);
        __syncthreads();
        for (int t = tid; t < NBINS; t += 256) {
            blkCnt[t * 256 + b] = min(hist[t], (unsigned)CAP_PB);
            hist[t] = 0;                   // reuse as local rank cursor
        }
        __syncthreads();
        for (int i = e0 + tid; i < e1; i += 256) {
            int s = s_idx[i];
            unsigned bin = (unsigned)s >> 7;
            unsigned r   = atomicAdd(&hist[bin], 1u);
            if (r < CAP_PB) {
                unsigned low = ((unsigned)a_idx[i] << 16)
                             | (unsigned)__half_as_ushort(__float2half(ew[i]));
                coarse[((size_t)bin * 256 + b) * CAP_PB + r] =
                    ((ull)((unsigned)s & 127u) << 32) | (ull)low;
            }
        }
    } else {
        // ---- prep role ----
        int pb     = blockIdx.x - 256;
        int gtid   = pb * 256 + tid;
        int stride = ((int)gridDim.x - 256) * 256;
        if (gtid == 0) { accum[0] = 0.f; accum[1] = 0.f; *done = 0; }

        for (int u = gtid; u < num_a * 16; u += stride) {
            int a    = u >> 4;
            int comp = (u & 15) << 3;          // 8 comps per thread
            const float* src = af + (size_t)a * D + comp;
            float4 v0 = *reinterpret_cast<const float4*>(src);
            float4 v1 = *reinterpret_cast<const float4*>(src + 4);
            unsigned lo = __builtin_amdgcn_cvt_pk_fp8_f32(v0.x, v0.y, 0u, false);
            lo = __builtin_amdgcn_cvt_pk_fp8_f32(v0.z, v0.w, lo, true);
            unsigned hi = __builtin_amdgcn_cvt_pk_fp8_f32(v1.x, v1.y, 0u, false);
            hi = __builtin_amdgcn_cvt_pk_fp8_f32(v1.z, v1.w, hi, true);
            int p  = comp >> 6;                // slice 0..1
            int cc = comp & 63;                // byte offset within 64B row
            *reinterpret_cast<ull*>(af_q + ((size_t)p * num_a + a) * 64 + cc) =
                ((ull)hi << 32) | (ull)lo;

            // sum of squares of the DECODED fp8 values (keeps the identity exact)
            f32x2 q0 = __builtin_amdgcn_cvt_pk_f32_fp8(lo, false);
            f32x2 q1 = __builtin_amdgcn_cvt_pk_f32_fp8(lo, true);
            f32x2 q2 = __builtin_amdgcn_cvt_pk_f32_fp8(hi, false);
            f32x2 q3 = __builtin_amdgcn_cvt_pk_f32_fp8(hi, true);
            float ss = q0.x*q0.x + q0.y*q0.y + q1.x*q1.x + q1.y*q1.y
                     + q2.x*q2.x + q2.y*q2.y + q3.x*q3.x + q3.y*q3.y;
            #pragma unroll
            for (int m = 1; m <= 8; m <<= 1) ss += __shfl_xor(ss, m, 64);
            if ((u & 15) == 0) sqnorm[a] = ss;
        }
    }
}

// ---------- B: final bucketing — block = bin, thread t drains region (bin,t) ----------

__global__ __launch_bounds__(256) void final_bucket(
    const ull* __restrict__ coarse,
    const unsigned* __restrict__ blkCnt,
    unsigned* __restrict__ bucket, int* __restrict__ cnt, int num_s)
{
    __shared__ unsigned lcnt[128];
    int bin = blockIdx.x;
    int tid = threadIdx.x;
    if (tid < 128) lcnt[tid] = 0;
    __syncthreads();
    unsigned c = blkCnt[bin * 256 + tid];
    const ull* reg = coarse + ((size_t)bin * 256 + tid) * CAP_PB;
    for (unsigned r = 0; r < c; ++r) {
        ull e = reg[r];
        unsigned s7 = (unsigned)(e >> 32);
        unsigned k  = atomicAdd(&lcnt[s7], 1u);
        if (k < KMAX) {
            int s = bin * 128 + (int)s7;
            bucket[((size_t)s << 6) + k] = (unsigned)e;
        }
    }
    __syncthreads();
    if (tid < 128) {
        int s = bin * 128 + tid;
        if (s < num_s) cnt[s] = (int)min(lcnt[tid], (unsigned)KMAX);
    }
}

// decode 16 fp8 (uint4) and FMA into acc[16] with weight w
__device__ __forceinline__ void fma16(const uint4& x, float w, float* acc) {
    f32x2 t;
    t = __builtin_amdgcn_cvt_pk_f32_fp8(x.x, false); acc[0]  += w*t.x; acc[1]  += w*t.y;
    t = __builtin_amdgcn_cvt_pk_f32_fp8(x.x, true);  acc[2]  += w*t.x; acc[3]  += w*t.y;
    t = __builtin_amdgcn_cvt_pk_f32_fp8(x.y, false); acc[4]  += w*t.x; acc[5]  += w*t.y;
    t = __builtin_amdgcn_cvt_pk_f32_fp8(x.y, true);  acc[6]  += w*t.x; acc[7]  += w*t.y;
    t = __builtin_amdgcn_cvt_pk_f32_fp8(x.z, false); acc[8]  += w*t.x; acc[9]  += w*t.y;
    t = __builtin_amdgcn_cvt_pk_f32_fp8(x.z, true);  acc[10] += w*t.x; acc[11] += w*t.y;
    t = __builtin_amdgcn_cvt_pk_f32_fp8(x.w, false); acc[12] += w*t.x; acc[13] += w*t.y;
    t = __builtin_amdgcn_cvt_pk_f32_fp8(x.w, true);  acc[14] += w*t.x; acc[15] += w*t.y;
}

// ---------- C: BOTH slices in one dispatch, role = blockIdx&1 (R19-proven) ----------

__global__ __launch_bounds__(256) void slice_merged(
    const unsigned char* __restrict__ af_q,   // [2][num_a][64] fp8
    const float* __restrict__ sqnorm,
    const unsigned* __restrict__ bucket,
    const int* __restrict__ cnt,
    float* __restrict__ fn2a, float* __restrict__ fn2b,
    float* __restrict__ s2acc, float* __restrict__ wsumv,
    int num_s, int num_a)
{
    const bool p0  = (blockIdx.x & 1u) == 0u;
    const unsigned char* afp = af_q + (p0 ? 0 : (size_t)num_a * 64);
    int lblk    = blockIdx.x >> 1;
    int gid     = lblk * 256 + threadIdx.x;
    int group   = gid >> 5;
    int lane    = threadIdx.x & 31;
    int j       = lane >> 2;       // edge slot 0..7
    int ccq     = lane & 3;        // 16B chunk (16 comps)
    int ngroups = ((gridDim.x >> 1) * 256) >> 5;

    for (int s0 = group * 2; s0 < num_s; s0 += ngroups * 2) {
        int s1 = s0 + 1;                       // NS even => s1 always valid
        int2 c2 = *reinterpret_cast<const int2*>(cnt + s0);
        int c0 = min(c2.x, KMAX);
        int c1 = min(c2.y, KMAX);
        const unsigned* b0 = bucket + ((size_t)s0 << 6);
        const unsigned* b1 = bucket + ((size_t)s1 << 6);

        float accA[16] = {};
        float accB[16] = {};
        float s2A = 0.f, wlA = 0.f, s2B = 0.f, wlB = 0.f;

        int cmax  = max(c0, c1);
        int iters = (cmax + 15) >> 4;          // 16 edges per s per iteration
        for (int it = 0; it < iters; ++it) {
            int idxA = it * 16 + j;            // slots j and j+8
            int idxB = idxA + 8;
            unsigned wa0  = (idxA < c0) ? b0[idxA] : 0u;   // inactive -> w=+0, row 0
            unsigned wa0b = (idxB < c0) ? b0[idxB] : 0u;
            unsigned wa1  = (idxA < c1) ? b1[idxA] : 0u;
            unsigned wa1b = (idxB < c1) ? b1[idxB] : 0u;
            float w0  = __half2float(__ushort_as_half((unsigned short)(wa0  & 0xFFFFu)));
            float w0b = __half2float(__ushort_as_half((unsigned short)(wa0b & 0xFFFFu)));
            float w1  = __half2float(__ushort_as_half((unsigned short)(wa1  & 0xFFFFu)));
            float w1b = __half2float(__ushort_as_half((unsigned short)(wa1b & 0xFFFFu)));
            int A0  = (int)(wa0  >> 16);
            int A0b = (int)(wa0b >> 16);
            int A1  = (int)(wa1  >> 16);
            int A1b = (int)(wa1b >> 16);
            uint4 x  = *reinterpret_cast<const uint4*>(afp + ((size_t)A0  << 6) + (ccq << 4));
            uint4 xb = *reinterpret_cast<const uint4*>(afp + ((size_t)A0b << 6) + (ccq << 4));
            uint4 y  = *reinterpret_cast<const uint4*>(afp + ((size_t)A1  << 6) + (ccq << 4));
            uint4 yb = *reinterpret_cast<const uint4*>(afp + ((size_t)A1b << 6) + (ccq << 4));
            fma16(x,  w0,  accA);
            fma16(xb, w0b, accA);
            fma16(y,  w1,  accB);
            fma16(yb, w1b, accB);
            if (p0 && ccq == 0) {
                s2A += w0 * sqnorm[A0] + w0b * sqnorm[A0b];  wlA += w0 + w0b;
                s2B += w1 * sqnorm[A1] + w1b * sqnorm[A1b];  wlB += w1 + w1b;
            }
        }
        // reduce over edge slots j (lane bits 2..4)
        #pragma unroll
        for (int m = 4; m <= 16; m <<= 1) {
            #pragma unroll
            for (int k = 0; k < 16; ++k) {
                accA[k] += __shfl_xor(accA[k], m, 64);
                accB[k] += __shfl_xor(accB[k], m, 64);
            }
            if (p0) {
                s2A += __shfl_xor(s2A, m, 64); wlA += __shfl_xor(wlA, m, 64);
                s2B += __shfl_xor(s2B, m, 64); wlB += __shfl_xor(wlB, m, 64);
            }
        }
        float n2a = 0.f, n2b = 0.f;
        #pragma unroll
        for (int k = 0; k < 16; ++k) { n2a += accA[k] * accA[k]; n2b += accB[k] * accB[k]; }
        n2a += __shfl_xor(n2a, 1, 64); n2a += __shfl_xor(n2a, 2, 64);
        n2b += __shfl_xor(n2b, 1, 64); n2b += __shfl_xor(n2b, 2, 64);
        if (lane == 0) {   // exclusive (role, s) owner — pure writes only
            if (p0) {
                fn2a[s0] = n2a;  s2acc[s0] = s2A;  wsumv[s0] = wlA;
                fn2a[s1] = n2b;  s2acc[s1] = s2B;  wsumv[s1] = wlB;
            } else {
                fn2b[s0] = n2a;
                fn2b[s1] = n2b;
            }
        }
    }
}

// ---------- D: loss reduction + last-block finalize (128 blocks: fence cost OK) ----------

__global__ void loss_finalize(const float* __restrict__ fn2a, const float* __restrict__ fn2b,
                              const float* __restrict__ s2acc, const float* __restrict__ wsumv,
                              float* __restrict__ accum, int* __restrict__ done,
                              float* __restrict__ out, int num_s) {
    __shared__ float sv[4], sc[4];
    float lv = 0.f, lc = 0.f;
    for (int s = blockIdx.x * blockDim.x + threadIdx.x; s < num_s; s += gridDim.x * blockDim.x) {
        float w = wsumv[s];
        if (w > 0.f) {
            float n2  = fn2a[s] + fn2b[s];
            float inv = 1.f / (w + 1e-8f);
            lv += s2acc[s] - n2 * inv * (2.f - w * inv);
            lc += 1.f;
        }
    }
    #pragma unroll
    for (int m = 1; m < 64; m <<= 1) { lv += __shfl_xor(lv, m, 64); lc += __shfl_xor(lc, m, 64); }
    int wv = threadIdx.x >> 6;
    if ((threadIdx.x & 63) == 0) { sv[wv] = lv; sc[wv] = lc; }
    __syncthreads();
    if (threadIdx.x == 0) {
        atomicAdd(accum + 0, sv[0] + sv[1] + sv[2] + sv[3]);
        atomicAdd(accum + 1, sc[0] + sc[1] + sc[2] + sc[3]);
        __threadfence();
        unsigned t = atomicAdd((unsigned*)done, 1u);
        if (t == gridDim.x - 1) {
            float v = atomicAdd(accum + 0, 0.f);   // device-scope RMW read
            float c = atomicAdd(accum + 1, 0.f);
            out[0] = (c > 0.f) ? (v / fmaxf(c, 1.f)) : 0.f;
        }
    }
}

extern "C" void kernel_launch(void* const* d_in, const int* in_sizes, int n_in,
                              void* d_out, int out_size, void* d_ws, size_t ws_size,
                              hipStream_t stream) {
    const float* ew = (const float*)d_in[0];          // [E]
    const float* af = (const float*)d_in[1];          // [NA, 128]
    const int*   ei = (const int*)d_in[2];            // [2, E] flat int32
    const int E     = in_sizes[0];
    const int num_a = in_sizes[1] / D;
    const int num_s = NS;

    const int* s_idx = ei;
    const int* a_idx = ei + E;

    // workspace carve-out (~47MB; d_ws ~268MB per harness poison fill)
    char* ws = (char*)d_ws;
    size_t off = 0;
    auto alloc = [&](size_t bytes, size_t align) -> char* {
        off = (off + align - 1) & ~(align - 1);
        char* p = ws + off;
        off += bytes;
        return p;
    };
    float* accum  = (float*)alloc(4 * 4, 16);          // accum[2] | done | pad
    int*   done   = (int*)(accum + 2);
    int*   cnt    = (int*)alloc((size_t)num_s * 4, 16);
    float* fn2a   = (float*)alloc((size_t)num_s * 4, 16);
    float* fn2b   = (float*)alloc((size_t)num_s * 4, 16);
    float* s2acc  = (float*)alloc((size_t)num_s * 4, 16);
    float* wsumv  = (float*)alloc((size_t)num_s * 4, 16);
    float* sqnorm = (float*)alloc((size_t)num_a * 4, 16);
    unsigned* blkCnt    = (unsigned*)alloc((size_t)NBINS * 256 * 4, 64);       // 400KB
    unsigned char* af_q = (unsigned char*)alloc((size_t)2 * num_a * 64, 256);  // 6.4MB fp8
    unsigned* bucket    = (unsigned*)alloc((size_t)num_s * KMAX * 4, 512);     // 12.8MB
    ull* coarse = (ull*)alloc((size_t)NBINS * 256 * CAP_PB * 8, 512);          // 25.6MB

    int prep_blocks = (num_a * 16 + 255) / 256;        // 3125
    prep_bin<<<256 + prep_blocks, 256, 0, stream>>>(af, af_q, sqnorm, accum, done,
                                                    s_idx, a_idx, ew, blkCnt, coarse,
                                                    E, num_a);
    final_bucket<<<NBINS, 256, 0, stream>>>(coarse, blkCnt, bucket, cnt, num_s);
    slice_merged<<<4096, 256, 0, stream>>>(af_q, sqnorm, bucket, cnt,
                                           fn2a, fn2b, s2acc, wsumv, num_s, num_a);
    loss_finalize<<<128, 256, 0, stream>>>(fn2a, fn2b, s2acc, wsumv, accum, done,
                                           (float*)d_out, num_s);
}